// Round 1
// baseline (628.172 us; speedup 1.0000x reference)
//
#include <hip/hip_runtime.h>
#include <cmath>
#include <cstdint>

#define DINL __device__ __forceinline__

namespace {

constexpr int Nn = 20000, Ee = 320000, Gg = 256, Dd = 256, Pp = 16;
constexpr float EPSf = 1e-7f, Rf = 0.5f, TEMPf = 0.2f;

DINL float waveSum(float x) {
#pragma unroll
  for (int off = 32; off > 0; off >>= 1) x += __shfl_xor(x, off, 64);
  return x;
}

// ---------- CSR build ----------
__global__ void k_deg(const int* __restrict__ dst, int* __restrict__ deg) {
  int e = blockIdx.x * 256 + threadIdx.x;
  if (e < Ee) atomicAdd(&deg[dst[e]], 1);
}

__global__ __launch_bounds__(1024) void k_scan(const int* __restrict__ deg,
                                               int* __restrict__ offs) {
  __shared__ int part[1024];
  int tid = threadIdx.x;
  const int chunk = (Nn + 1023) >> 10;  // 20
  int start = tid * chunk;
  int s = 0;
  for (int k = 0; k < chunk; k++) { int i = start + k; if (i < Nn) s += deg[i]; }
  part[tid] = s;
  __syncthreads();
  for (int off = 1; off < 1024; off <<= 1) {
    int v = (tid >= off) ? part[tid - off] : 0;
    __syncthreads();
    part[tid] += v;
    __syncthreads();
  }
  int run = (tid == 0) ? 0 : part[tid - 1];
  for (int k = 0; k < chunk; k++) {
    int i = start + k;
    if (i < Nn) { offs[i] = run; run += deg[i]; }
  }
  if (start < Nn && start + chunk >= Nn) offs[Nn] = run;
}

__global__ void k_fill(const int* __restrict__ src, const int* __restrict__ dst,
                       const int* __restrict__ offs, int* __restrict__ cursor,
                       int* __restrict__ csr) {
  int e = blockIdx.x * 256 + threadIdx.x;
  if (e < Ee) {
    int d = dst[e];
    int pos = atomicAdd(&cursor[d], 1);
    csr[offs[d] + pos] = src[e];
  }
}

// graph offsets from sorted batch
__global__ void k_goff(const int* __restrict__ batch, int* __restrict__ goff) {
  int i = blockIdx.x * 256 + threadIdx.x;
  if (i >= Nn) return;
  int bi = batch[i];
  int bp = (i == 0) ? -1 : batch[i - 1];
  for (int g = bp + 1; g <= bi; ++g) goff[g] = i;
  if (i == Nn - 1)
    for (int g = bi + 1; g <= Gg; ++g) goff[g] = Nn;
}

// ---------- edge aggregation: one wave per node ----------
// MODE 0: out[i] = h[i] + sum_s h[s]
// MODE 1: out[i] = nb[i]*( h[i] + sum_s h[s]*nb[s]^2 )      (pass2 conv1, h = x)
// MODE 2: out[i] = h[i] + nb[i]*sum_s h[s]*nb[s]            (pass2 conv2)
template <int DIM, int MODE>
__global__ void k_agg(const float* __restrict__ h, const float* __restrict__ nb,
                      const int* __restrict__ offs, const int* __restrict__ csr,
                      float* __restrict__ out) {
  constexpr int V = DIM / 64;  // 2 or 4 floats per lane
  int gw = (blockIdx.x * 256 + threadIdx.x) >> 6;
  int lane = threadIdx.x & 63;
  if (gw >= Nn) return;
  const float* selfRow = h + (size_t)gw * DIM + lane * V;
  float acc[V], tsum[V];
  if (V == 4) {
    float4 t = *(const float4*)selfRow;
    acc[0] = t.x; acc[1] = t.y; acc[2] = t.z; acc[3] = t.w;
  } else {
    float2 t = *(const float2*)selfRow;
    acc[0] = t.x; acc[1] = t.y;
  }
#pragma unroll
  for (int j = 0; j < V; j++) tsum[j] = 0.f;
  int beg = offs[gw], end = offs[gw + 1];
  for (int k = beg; k < end; k++) {
    int s = csr[k];
    const float* row = h + (size_t)s * DIM + lane * V;
    float r[V];
    if (V == 4) {
      float4 t = *(const float4*)row;
      r[0] = t.x; r[1] = t.y; r[2] = t.z; r[3] = t.w;
    } else {
      float2 t = *(const float2*)row;
      r[0] = t.x; r[1] = t.y;
    }
    if (MODE == 0) {
#pragma unroll
      for (int j = 0; j < V; j++) acc[j] += r[j];
    } else if (MODE == 1) {
      float q = nb[s]; float w = q * q;
#pragma unroll
      for (int j = 0; j < V; j++) tsum[j] += w * r[j];
    } else {
      float w = nb[s];
#pragma unroll
      for (int j = 0; j < V; j++) tsum[j] += w * r[j];
    }
  }
  if (MODE == 1) {
    float wi = nb[gw];
#pragma unroll
    for (int j = 0; j < V; j++) acc[j] = wi * (acc[j] + tsum[j]);
  } else if (MODE == 2) {
    float wi = nb[gw];
#pragma unroll
    for (int j = 0; j < V; j++) acc[j] += wi * tsum[j];
  }
  float* orow = out + (size_t)gw * DIM + lane * V;
  if (V == 4) {
    *(float4*)orow = make_float4(acc[0], acc[1], acc[2], acc[3]);
  } else {
    *(float2*)orow = make_float2(acc[0], acc[1]);
  }
}

// ---------- tiled f32 GEMM: C[N,256] = act(A[N,K] @ B[K,256] + row/col add) ----------
// MODE 0: out[r][c] = relu(acc + bias[c])
// MODE 1: t = relu(acc + pc[assign[batch[r]]][c]); prob[r] += sum_c t*Wm2[c] (atomic)
template <int K, int MODE>
__global__ __launch_bounds__(256) void k_gemm(
    const float* __restrict__ A, const float* __restrict__ B,
    const float* __restrict__ bias, float* __restrict__ out,
    const float* __restrict__ pc, const int* __restrict__ batch,
    const int* __restrict__ assign, const float* __restrict__ Wm2,
    float* __restrict__ prob) {
  __shared__ float As[16][64];
  __shared__ float Bs[16][64];
  __shared__ float red[64][16];
  __shared__ int ap_s[64];
  int tid = threadIdx.x;
  int tx = tid & 15, ty = tid >> 4;
  int rowBase = blockIdx.y * 64, colBase = blockIdx.x * 64;
  if (MODE == 1 && tid < 64) {
    int r = rowBase + tid;
    ap_s[tid] = (r < Nn) ? assign[batch[r]] : 0;
  }
  float acc[4][4] = {};
  int aRow = tid >> 2;
  int aK = (tid & 3) * 4;
  int bK = tid >> 4;
  int bC = (tid & 15) * 4;
  for (int k0 = 0; k0 < K; k0 += 16) {
    int ar = rowBase + aRow;
    float4 av = make_float4(0.f, 0.f, 0.f, 0.f);
    if (ar < Nn) av = *(const float4*)(A + (size_t)ar * K + k0 + aK);
    float4 bv = *(const float4*)(B + (size_t)(k0 + bK) * Dd + colBase + bC);
    As[aK + 0][aRow] = av.x;
    As[aK + 1][aRow] = av.y;
    As[aK + 2][aRow] = av.z;
    As[aK + 3][aRow] = av.w;
    *(float4*)&Bs[bK][bC] = bv;
    __syncthreads();
#pragma unroll
    for (int kk = 0; kk < 16; kk++) {
      float4 a = *(const float4*)&As[kk][ty * 4];
      float4 b = *(const float4*)&Bs[kk][tx * 4];
      acc[0][0] += a.x * b.x; acc[0][1] += a.x * b.y; acc[0][2] += a.x * b.z; acc[0][3] += a.x * b.w;
      acc[1][0] += a.y * b.x; acc[1][1] += a.y * b.y; acc[1][2] += a.y * b.z; acc[1][3] += a.y * b.w;
      acc[2][0] += a.z * b.x; acc[2][1] += a.z * b.y; acc[2][2] += a.z * b.z; acc[2][3] += a.z * b.w;
      acc[3][0] += a.w * b.x; acc[3][1] += a.w * b.y; acc[3][2] += a.w * b.z; acc[3][3] += a.w * b.w;
    }
    __syncthreads();
  }
  int c = colBase + tx * 4;
  if (MODE == 0) {
    float4 bv = *(const float4*)&bias[c];
#pragma unroll
    for (int i = 0; i < 4; i++) {
      int r = rowBase + ty * 4 + i;
      if (r < Nn) {
        float4 o;
        o.x = fmaxf(acc[i][0] + bv.x, 0.f);
        o.y = fmaxf(acc[i][1] + bv.y, 0.f);
        o.z = fmaxf(acc[i][2] + bv.z, 0.f);
        o.w = fmaxf(acc[i][3] + bv.w, 0.f);
        *(float4*)(out + (size_t)r * Dd + c) = o;
      }
    }
  } else {
    float4 wm = *(const float4*)&Wm2[c];
#pragma unroll
    for (int i = 0; i < 4; i++) {
      int ap = ap_s[ty * 4 + i];
      float4 pcv = *(const float4*)&pc[ap * Dd + c];
      float t0 = fmaxf(acc[i][0] + pcv.x, 0.f);
      float t1 = fmaxf(acc[i][1] + pcv.y, 0.f);
      float t2 = fmaxf(acc[i][2] + pcv.z, 0.f);
      float t3 = fmaxf(acc[i][3] + pcv.w, 0.f);
      red[ty * 4 + i][tx] = t0 * wm.x + t1 * wm.y + t2 * wm.z + t3 * wm.w;
    }
    __syncthreads();
    if (tid < 64) {
      float s = 0.f;
#pragma unroll
      for (int t = 0; t < 16; t++) s += red[tid][t];
      int r = rowBase + tid;
      if (r < Nn) atomicAdd(&prob[r], s);
    }
  }
}

// ---------- pooling: one block per graph ----------
__global__ void k_pool(const float* __restrict__ h, const int* __restrict__ goff,
                       float* __restrict__ gout, float* __restrict__ gout2) {
  int g = blockIdx.x, c = threadIdx.x;
  int beg = goff[g], end = goff[g + 1];
  float s = 0.f;
  for (int n = beg; n < end; ++n) s += h[(size_t)n * Dd + c];
  gout[g * Dd + c] = s;
  if (gout2 != nullptr) gout2[g * Dd + c] = s;
}

// ---------- proto_contrib + proto norms ----------
__global__ void k_pc(const float* __restrict__ proto, const float* __restrict__ Wm1,
                     const float* __restrict__ bm1, float* __restrict__ pc,
                     float* __restrict__ pnorm) {
  int p = blockIdx.x, c = threadIdx.x;
  float s = bm1[c];
  for (int k = 0; k < Dd; k++) s += proto[p * Dd + k] * Wm1[(size_t)(Dd + k) * Dd + c];
  pc[p * Dd + c] = s;
  __shared__ float redn[256];
  float v = proto[p * Dd + c];
  redn[c] = v * v;
  __syncthreads();
  for (int off = 128; off > 0; off >>= 1) {
    if (c < off) redn[c] += redn[c + off];
    __syncthreads();
  }
  if (c == 0) {
    float n = sqrtf(redn[0]);
    pnorm[p] = (n == 0.f) ? EPSf : n;
  }
}

// ---------- cosine argmax (pass 1) ----------
__global__ __launch_bounds__(64) void k_assign(const float* __restrict__ ge,
                                               const float* __restrict__ proto,
                                               const float* __restrict__ pnorm,
                                               int* __restrict__ assign) {
  int g = blockIdx.x, lane = threadIdx.x;
  float4 v = *(const float4*)(ge + (size_t)g * Dd + lane * 4);
  float na = sqrtf(waveSum(v.x * v.x + v.y * v.y + v.z * v.z + v.w * v.w));
  if (na == 0.f) na = EPSf;
  float best = -1e30f;
  int bi = 0;
#pragma unroll
  for (int p = 0; p < Pp; p++) {
    float4 w = *(const float4*)(proto + (size_t)p * Dd + lane * 4);
    float d = waveSum(v.x * w.x + v.y * w.y + v.z * w.z + v.w * w.w);
    float sim = d / (na * pnorm[p]);
    if (sim > best) { best = sim; bi = p; }
  }
  if (lane == 0) assign[g] = bi;
}

// ---------- similarity + NCE (pass 2) ----------
__global__ __launch_bounds__(64) void k_simnce(const float* __restrict__ se,
                                               const float* __restrict__ proto,
                                               const float* __restrict__ pnorm,
                                               float* __restrict__ osim,
                                               float* __restrict__ snorm,
                                               float* __restrict__ nceAcc) {
  int g = blockIdx.x, lane = threadIdx.x;
  float4 v = *(const float4*)(se + (size_t)g * Dd + lane * 4);
  float na = sqrtf(waveSum(v.x * v.x + v.y * v.y + v.z * v.z + v.w * v.w));
  if (na == 0.f) na = EPSf;
  float sims[Pp];
#pragma unroll
  for (int p = 0; p < Pp; p++) {
    float4 w = *(const float4*)(proto + (size_t)p * Dd + lane * 4);
    float d = waveSum(v.x * w.x + v.y * w.y + v.z * w.z + v.w * w.w);
    float sim = d / (na * pnorm[p]);
    sims[p] = sim;
    if (lane == p) osim[g * Pp + p] = sim;
  }
  float best = sims[0];
  int bi = 0;
#pragma unroll
  for (int p = 1; p < Pp; p++) {
    if (sims[p] > best) { best = sims[p]; bi = p; }
  }
  float pos = 0.f, neg = 0.f;
#pragma unroll
  for (int p = 0; p < Pp; p++) {
    float e = expf(sims[p] / TEMPf);
    if (p == bi) pos = e; else neg += e;
  }
  float lg = -logf(pos / neg);
  if (lane == 0) {
    atomicAdd(nceAcc, lg);
    snorm[g] = na;
  }
}

// ---------- node_bern / edge_bern ----------
__global__ void k_bern(const float* __restrict__ prob, const float* __restrict__ bm2,
                       float* __restrict__ ob) {
  int i = blockIdx.x * 256 + threadIdx.x;
  if (i < Nn) {
    float z = prob[i] + bm2[0];
    ob[i] = 1.f / (1.f + expf(-z));
  }
}

__global__ void k_eb(const int* __restrict__ src, const int* __restrict__ dst,
                     const float* __restrict__ nb, float* __restrict__ oe) {
  int e = blockIdx.x * 256 + threadIdx.x;
  if (e < Ee) oe[e] = nb[src[e]] * nb[dst[e]];
}

// ---------- KL reduction ----------
__global__ void k_kl(const float* __restrict__ v, int n, float invA, float invB,
                     float* __restrict__ acc) {
  int i = blockIdx.x * 256 + threadIdx.x;
  float val = 0.f;
  if (i < n) {
    float xv = v[i];
    val = xv * logf(xv * invA + EPSf) + (1.f - xv) * logf((1.f - xv) * invB + EPSf);
  }
  val = waveSum(val);
  __shared__ float wsum[4];
  int lane = threadIdx.x & 63, wv = threadIdx.x >> 6;
  if (lane == 0) wsum[wv] = val;
  __syncthreads();
  if (threadIdx.x == 0) atomicAdd(acc, wsum[0] + wsum[1] + wsum[2] + wsum[3]);
}

__global__ void k_fin(const float* __restrict__ accs, float* __restrict__ o_kl,
                      float* __restrict__ o_nce) {
  o_kl[0] = accs[0] / (float)Nn + accs[1] / (float)Ee;
  o_nce[0] = accs[2] / (float)Gg;
}

// ---------- data_sim ----------
__global__ void k_datasim(const float* __restrict__ S, const float* __restrict__ snorm,
                          float* __restrict__ out) {
  __shared__ float si[Dd];
  int i = blockIdx.x, j = threadIdx.x;
  si[j] = S[(size_t)i * Dd + j];
  __syncthreads();
  const float4* rj = (const float4*)(S + (size_t)j * Dd);
  const float4* sif = (const float4*)si;
  float d = 0.f;
#pragma unroll 4
  for (int k = 0; k < Dd / 4; k++) {
    float4 a = sif[k];
    float4 b = rj[k];
    d += a.x * b.x + a.y * b.y + a.z * b.z + a.w * b.w;
  }
  out[(size_t)i * Gg + j] = d / (snorm[i] * snorm[j]);
}

__global__ void k_copy2(const float2* __restrict__ s, float2* __restrict__ d, int n) {
  int i = blockIdx.x * 256 + threadIdx.x;
  if (i < n) d[i] = s[i];
}

}  // namespace

extern "C" void kernel_launch(void* const* d_in, const int* in_sizes, int n_in,
                              void* d_out, int out_size, void* d_ws, size_t ws_size,
                              hipStream_t stream) {
  const float* x = (const float*)d_in[0];
  const int* ei = (const int*)d_in[1];
  const int* batch = (const int*)d_in[2];
  const float* W1 = (const float*)d_in[3];
  const float* b1 = (const float*)d_in[4];
  const float* W2 = (const float*)d_in[5];
  const float* b2 = (const float*)d_in[6];
  const float* Wm1 = (const float*)d_in[7];
  const float* bm1 = (const float*)d_in[8];
  const float* Wm2 = (const float*)d_in[9];
  const float* bm2 = (const float*)d_in[10];
  const float* proto = (const float*)d_in[11];
  const int* src = ei;
  const int* dst = ei + Ee;

  float* out = (float*)d_out;
  float* o_kl = out;                 // 1
  float* o_nce = out + 1;            // 1
  float* o_sim = out + 2;            // G*P
  float* o_nb = o_sim + Gg * Pp;     // N
  float* o_eb = o_nb + Nn;           // E
  float* o_ds = o_eb + Ee;           // G*G
  float* o_sg = o_ds + Gg * Gg;      // G*D
  float* o_ne = o_sg + Gg * Dd;      // N*D

  char* w = (char*)d_ws;
  auto take = [&](size_t bytes) -> char* {
    char* p = w;
    w += (bytes + 255) & ~(size_t)255;
    return p;
  };
  float* bufA = (float*)take((size_t)Nn * Dd * 4);
  float* bufB = (float*)take((size_t)Nn * Dd * 4);
  int* csr = (int*)take((size_t)Ee * 4);
  int* deg = (int*)take((size_t)Nn * 4);
  int* cursor = (int*)take((size_t)Nn * 4);
  int* offs = (int*)take((size_t)(Nn + 1) * 4);
  int* goff = (int*)take((size_t)(Gg + 1) * 4);
  float* gemb = (float*)take((size_t)Gg * Dd * 4);
  float* sgemb = (float*)take((size_t)Gg * Dd * 4);
  float* pc = (float*)take((size_t)Pp * Dd * 4);
  float* pnorm = (float*)take(Pp * 4);
  int* assign = (int*)take(Gg * 4);
  float* snorm = (float*)take(Gg * 4);
  float* prob = (float*)take(Nn * 4);
  float* accs = (float*)take(16);

  hipMemsetAsync(deg, 0, Nn * 4, stream);
  hipMemsetAsync(cursor, 0, Nn * 4, stream);
  hipMemsetAsync(prob, 0, Nn * 4, stream);
  hipMemsetAsync(accs, 0, 16, stream);

  const int eB = (Ee + 255) / 256;
  const int nB = (Nn + 255) / 256;
  const int aggB = (Nn * 64 + 255) / 256;
  dim3 gg(Dd / 64, (Nn + 63) / 64);

  k_deg<<<eB, 256, 0, stream>>>(dst, deg);
  k_scan<<<1, 1024, 0, stream>>>(deg, offs);
  k_fill<<<eB, 256, 0, stream>>>(src, dst, offs, cursor, csr);
  k_goff<<<nB, 256, 0, stream>>>(batch, goff);
  k_pc<<<Pp, 256, 0, stream>>>(proto, Wm1, bm1, pc, pnorm);

  // ---- pass 1 ----
  k_agg<128, 0><<<aggB, 256, 0, stream>>>(x, nullptr, offs, csr, bufA);
  k_gemm<128, 0><<<gg, 256, 0, stream>>>(bufA, W1, b1, bufB, nullptr, nullptr,
                                         nullptr, nullptr, nullptr);
  k_agg<256, 0><<<aggB, 256, 0, stream>>>(bufB, nullptr, offs, csr, bufA);
  k_gemm<256, 0><<<gg, 256, 0, stream>>>(bufA, W2, b2, bufB, nullptr, nullptr,
                                         nullptr, nullptr, nullptr);  // node_embs -> bufB
  k_pool<<<Gg, 256, 0, stream>>>(bufB, goff, gemb, nullptr);
  k_assign<<<Gg, 64, 0, stream>>>(gemb, proto, pnorm, assign);
  k_gemm<256, 1><<<gg, 256, 0, stream>>>(bufB, Wm1, nullptr, nullptr, pc, batch,
                                         assign, Wm2, prob);
  k_bern<<<nB, 256, 0, stream>>>(prob, bm2, o_nb);
  k_eb<<<eB, 256, 0, stream>>>(src, dst, o_nb, o_eb);
  k_copy2<<<(Nn * Dd / 2 + 255) / 256, 256, 0, stream>>>((const float2*)bufB,
                                                         (float2*)o_ne, Nn * Dd / 2);

  // ---- pass 2 ----
  k_agg<128, 1><<<aggB, 256, 0, stream>>>(x, o_nb, offs, csr, bufA);
  k_gemm<128, 0><<<gg, 256, 0, stream>>>(bufA, W1, b1, bufB, nullptr, nullptr,
                                         nullptr, nullptr, nullptr);
  k_agg<256, 2><<<aggB, 256, 0, stream>>>(bufB, o_nb, offs, csr, bufA);
  k_gemm<256, 0><<<gg, 256, 0, stream>>>(bufA, W2, b2, bufB, nullptr, nullptr,
                                         nullptr, nullptr, nullptr);  // h2b -> bufB
  k_pool<<<Gg, 256, 0, stream>>>(bufB, goff, sgemb, o_sg);

  k_simnce<<<Gg, 64, 0, stream>>>(sgemb, proto, pnorm, o_sim, snorm, accs + 2);
  k_kl<<<nB, 256, 0, stream>>>(o_nb, Nn, 1.f / Rf, 1.f / (1.f - Rf + EPSf), accs + 0);
  k_kl<<<eB, 256, 0, stream>>>(o_eb, Ee, 1.f / (Rf * Rf), 1.f / (1.f - Rf * Rf + EPSf),
                               accs + 1);
  k_fin<<<1, 1, 0, stream>>>(accs, o_kl, o_nce);
  k_datasim<<<Gg, 256, 0, stream>>>(sgemb, snorm, o_ds);
}

// Round 2
// 489.135 us; speedup vs baseline: 1.2843x; 1.2843x over previous
//
#include <hip/hip_runtime.h>
#include <cmath>
#include <cstdint>

#define DINL __device__ __forceinline__

namespace {

constexpr int Nn = 20000, Ee = 320000, Gg = 256, Dd = 256, Pp = 16;
constexpr int Npad = 20096;  // 157 * 128
constexpr float EPSf = 1e-7f, Rf = 0.5f, TEMPf = 0.2f;

typedef unsigned short u16;
typedef __attribute__((ext_vector_type(8))) short short8;
typedef __attribute__((ext_vector_type(4))) float floatx4;

DINL float waveSum(float x) {
#pragma unroll
  for (int off = 32; off > 0; off >>= 1) x += __shfl_xor(x, off, 64);
  return x;
}

DINL u16 f2bf(float f) {
  unsigned u = __float_as_uint(f);
  unsigned r = u + 0x7fffu + ((u >> 16) & 1u);
  return (u16)(r >> 16);
}
DINL float bf2f(u16 h) { return __uint_as_float(((unsigned)h) << 16); }

// ---------- CSR build ----------
__global__ void k_deg(const int* __restrict__ dst, int* __restrict__ deg) {
  int e = blockIdx.x * 256 + threadIdx.x;
  if (e < Ee) atomicAdd(&deg[dst[e]], 1);
}

__global__ __launch_bounds__(1024) void k_scan(const int* __restrict__ deg,
                                               int* __restrict__ offs) {
  __shared__ int part[1024];
  int tid = threadIdx.x;
  const int chunk = (Nn + 1023) >> 10;
  int start = tid * chunk;
  int s = 0;
  for (int k = 0; k < chunk; k++) { int i = start + k; if (i < Nn) s += deg[i]; }
  part[tid] = s;
  __syncthreads();
  for (int off = 1; off < 1024; off <<= 1) {
    int v = (tid >= off) ? part[tid - off] : 0;
    __syncthreads();
    part[tid] += v;
    __syncthreads();
  }
  int run = (tid == 0) ? 0 : part[tid - 1];
  for (int k = 0; k < chunk; k++) {
    int i = start + k;
    if (i < Nn) { offs[i] = run; run += deg[i]; }
  }
  if (start < Nn && start + chunk >= Nn) offs[Nn] = run;
}

__global__ void k_fill(const int* __restrict__ src, const int* __restrict__ dst,
                       const int* __restrict__ offs, int* __restrict__ cursor,
                       int* __restrict__ csr) {
  int e = blockIdx.x * 256 + threadIdx.x;
  if (e < Ee) {
    int d = dst[e];
    int pos = atomicAdd(&cursor[d], 1);
    csr[offs[d] + pos] = src[e];
  }
}

__global__ void k_goff(const int* __restrict__ batch, int* __restrict__ goff) {
  int i = blockIdx.x * 256 + threadIdx.x;
  if (i >= Nn) return;
  int bi = batch[i];
  int bp = (i == 0) ? -1 : batch[i - 1];
  for (int g = bp + 1; g <= bi; ++g) goff[g] = i;
  if (i == Nn - 1)
    for (int g = bi + 1; g <= Gg; ++g) goff[g] = Nn;
}

// ---------- row load helper ----------
template <int V, bool INBF>
DINL void loadRow(float r[V], const void* __restrict__ hv, int row, int lane) {
  if constexpr (INBF) {
    const u16* p = (const u16*)hv + (size_t)row * (V * 64) + lane * V;
    if constexpr (V == 4) {
      ushort4 u = *(const ushort4*)p;
      r[0] = bf2f(u.x); r[1] = bf2f(u.y); r[2] = bf2f(u.z); r[3] = bf2f(u.w);
    } else {
      ushort2 u = *(const ushort2*)p;
      r[0] = bf2f(u.x); r[1] = bf2f(u.y);
    }
  } else {
    const float* p = (const float*)hv + (size_t)row * (V * 64) + lane * V;
    if constexpr (V == 4) {
      float4 u = *(const float4*)p;
      r[0] = u.x; r[1] = u.y; r[2] = u.z; r[3] = u.w;
    } else {
      float2 u = *(const float2*)p;
      r[0] = u.x; r[1] = u.y;
    }
  }
}

// ---------- edge aggregation (one wave/node, 4-deep pipelined gathers) ----------
// MODE 0: v = h[i] + sum_s h[s]                       (-> split hi/lo out)
// MODE 1: v = nb[i]*( h[i] + sum_s h[s]*nb[s]^2 )     (-> hi out)
// MODE 2: v = h[i] + nb[i]*sum_s h[s]*nb[s]           (-> hi out)
template <int DIM, int MODE, bool INBF, bool OSPL>
__global__ void k_agg(const void* __restrict__ hv, const float* __restrict__ nb,
                      const int* __restrict__ offs, const int* __restrict__ csr,
                      u16* __restrict__ oh, u16* __restrict__ ol) {
  constexpr int V = DIM / 64;
  int gw = (blockIdx.x * 256 + threadIdx.x) >> 6;
  int lane = threadIdx.x & 63;
  if (gw >= Nn) return;
  float self[V], ts[V];
  loadRow<V, INBF>(self, hv, gw, lane);
#pragma unroll
  for (int j = 0; j < V; j++) ts[j] = 0.f;
  int beg = offs[gw], end = offs[gw + 1];
  int k = beg;
  for (; k + 4 <= end; k += 4) {
    int s0 = csr[k], s1 = csr[k + 1], s2 = csr[k + 2], s3 = csr[k + 3];
    float r0[V], r1[V], r2[V], r3[V];
    loadRow<V, INBF>(r0, hv, s0, lane);
    loadRow<V, INBF>(r1, hv, s1, lane);
    loadRow<V, INBF>(r2, hv, s2, lane);
    loadRow<V, INBF>(r3, hv, s3, lane);
    if (MODE == 0) {
#pragma unroll
      for (int j = 0; j < V; j++) ts[j] += (r0[j] + r1[j]) + (r2[j] + r3[j]);
    } else {
      float w0 = nb[s0], w1 = nb[s1], w2 = nb[s2], w3 = nb[s3];
      if (MODE == 1) { w0 *= w0; w1 *= w1; w2 *= w2; w3 *= w3; }
#pragma unroll
      for (int j = 0; j < V; j++)
        ts[j] += (w0 * r0[j] + w1 * r1[j]) + (w2 * r2[j] + w3 * r3[j]);
    }
  }
  for (; k < end; k++) {
    int s = csr[k];
    float r[V];
    loadRow<V, INBF>(r, hv, s, lane);
    float w = 1.f;
    if (MODE == 1) { float q = nb[s]; w = q * q; }
    else if (MODE == 2) w = nb[s];
    if (MODE == 0) {
#pragma unroll
      for (int j = 0; j < V; j++) ts[j] += r[j];
    } else {
#pragma unroll
      for (int j = 0; j < V; j++) ts[j] += w * r[j];
    }
  }
  float val[V];
  if (MODE == 0) {
#pragma unroll
    for (int j = 0; j < V; j++) val[j] = self[j] + ts[j];
  } else if (MODE == 1) {
    float wi = nb[gw];
#pragma unroll
    for (int j = 0; j < V; j++) val[j] = wi * (self[j] + ts[j]);
  } else {
    float wi = nb[gw];
#pragma unroll
    for (int j = 0; j < V; j++) val[j] = self[j] + wi * ts[j];
  }
  u16 hs[V], ls[V];
#pragma unroll
  for (int j = 0; j < V; j++) {
    hs[j] = f2bf(val[j]);
    if (OSPL) ls[j] = f2bf(val[j] - bf2f(hs[j]));
  }
  u16* po = oh + (size_t)gw * DIM + lane * V;
  if constexpr (V == 4) {
    *(ushort4*)po = make_ushort4(hs[0], hs[1], hs[2], hs[3]);
  } else {
    *(ushort2*)po = make_ushort2(hs[0], hs[1]);
  }
  if constexpr (OSPL) {
    u16* pl = ol + (size_t)gw * DIM + lane * V;
    if constexpr (V == 4) {
      *(ushort4*)pl = make_ushort4(ls[0], ls[1], ls[2], ls[3]);
    } else {
      *(ushort2*)pl = make_ushort2(ls[0], ls[1]);
    }
  }
}

// ---------- MFMA GEMM: C[M,256] = A[M,K] @ B[K,256], A/Bt pre-split bf16 ----------
// Block 128x64 C-tile, 4 waves (each 32x64 via 2x4 MFMA 16x16x32 tiles).
// SPLIT: 3 MFMAs (hh + hl + lh) ~= fp32 precision.
// MODE 0: v = relu(acc + bias[c]); write outF/outH/outL (null-guarded).
// MODE 1 (masker): t = relu(acc + pc[assign[batch[r]]][c]); prob[r] += t.Wm2[c]
template <int K, bool SPLIT, int MODE>
__global__ __launch_bounds__(256) void k_mm(
    const u16* __restrict__ Ah, const u16* __restrict__ Al,
    const u16* __restrict__ Bh, const u16* __restrict__ Bl,
    const float* __restrict__ bias,
    float* __restrict__ outF, u16* __restrict__ outH, u16* __restrict__ outL,
    const float* __restrict__ pc, const int* __restrict__ batch,
    const int* __restrict__ assign, const float* __restrict__ Wm2,
    float* __restrict__ prob) {
  constexpr int SK = 40;  // padded k-stride (bf16): 80B rows, 16B-aligned, 2-way banks
  __shared__ u16 AsH[128 * SK];
  __shared__ u16 AsL[SPLIT ? 128 * SK : 16];
  __shared__ u16 BsH[64 * SK];
  __shared__ u16 BsL[SPLIT ? 64 * SK : 16];
  __shared__ int ap_s[128];
  int t = threadIdx.x;
  int rowBase = blockIdx.y * 128, colBase = blockIdx.x * 64;
  if (MODE == 1 && t < 128) {
    int r = rowBase + t;
    ap_s[t] = (r < Nn) ? assign[batch[r]] : 0;
  }
  int lane = t & 63, wv = t >> 6;
  int quad = lane >> 4, l16 = lane & 15;
  int wm = wv * 32;
  floatx4 acc[2][4];
#pragma unroll
  for (int mt = 0; mt < 2; mt++)
#pragma unroll
    for (int nt = 0; nt < 4; nt++) acc[mt][nt] = (floatx4){0.f, 0.f, 0.f, 0.f};

  int ar = t >> 1;               // 0..127 A-row within tile
  int akh = (t & 1) * 16;        // k offset (bf16)
  const u16* agH = Ah + (size_t)(rowBase + ar) * K + akh;
  const u16* agL = Al + (size_t)(rowBase + ar) * K + akh;
  int bn = t >> 2;               // 0..63 Bt-row within tile
  int bko = (t & 3) * 8;
  const u16* bgH = Bh + (size_t)(colBase + bn) * K + bko;
  const u16* bgL = Bl + (size_t)(colBase + bn) * K + bko;

  for (int k0 = 0; k0 < K; k0 += 32) {
    uint4 a0 = *(const uint4*)(agH + k0);
    uint4 a1 = *(const uint4*)(agH + k0 + 8);
    uint4 b0 = *(const uint4*)(bgH + k0);
    uint4 a0l, a1l, b0l;
    if constexpr (SPLIT) {
      a0l = *(const uint4*)(agL + k0);
      a1l = *(const uint4*)(agL + k0 + 8);
      b0l = *(const uint4*)(bgL + k0);
    }
    __syncthreads();
    *(uint4*)&AsH[ar * SK + akh] = a0;
    *(uint4*)&AsH[ar * SK + akh + 8] = a1;
    *(uint4*)&BsH[bn * SK + bko] = b0;
    if constexpr (SPLIT) {
      *(uint4*)&AsL[ar * SK + akh] = a0l;
      *(uint4*)&AsL[ar * SK + akh + 8] = a1l;
      *(uint4*)&BsL[bn * SK + bko] = b0l;
    }
    __syncthreads();
    short8 aH[2], aL[2], bH[4], bL[4];
#pragma unroll
    for (int mt = 0; mt < 2; mt++) {
      int off = (wm + mt * 16 + l16) * SK + quad * 8;
      aH[mt] = *(const short8*)&AsH[off];
      if (SPLIT) aL[mt] = *(const short8*)&AsL[off];
    }
#pragma unroll
    for (int nt = 0; nt < 4; nt++) {
      int off = (nt * 16 + l16) * SK + quad * 8;
      bH[nt] = *(const short8*)&BsH[off];
      if (SPLIT) bL[nt] = *(const short8*)&BsL[off];
    }
#pragma unroll
    for (int mt = 0; mt < 2; mt++)
#pragma unroll
      for (int nt = 0; nt < 4; nt++) {
        acc[mt][nt] = __builtin_amdgcn_mfma_f32_16x16x32_bf16(aH[mt], bH[nt], acc[mt][nt], 0, 0, 0);
        if constexpr (SPLIT) {
          acc[mt][nt] = __builtin_amdgcn_mfma_f32_16x16x32_bf16(aH[mt], bL[nt], acc[mt][nt], 0, 0, 0);
          acc[mt][nt] = __builtin_amdgcn_mfma_f32_16x16x32_bf16(aL[mt], bH[nt], acc[mt][nt], 0, 0, 0);
        }
      }
  }

  if constexpr (MODE == 0) {
#pragma unroll
    for (int mt = 0; mt < 2; mt++)
#pragma unroll
      for (int nt = 0; nt < 4; nt++) {
        int col = colBase + nt * 16 + l16;
        float bv = bias[col];
#pragma unroll
        for (int r = 0; r < 4; r++) {
          int row = rowBase + wm + mt * 16 + quad * 4 + r;
          if (row < Nn) {
            float v = fmaxf(acc[mt][nt][r] + bv, 0.f);
            size_t o = (size_t)row * 256 + col;
            if (outF) outF[o] = v;
            if (outH) {
              u16 hh = f2bf(v);
              outH[o] = hh;
              if (outL) outL[o] = f2bf(v - bf2f(hh));
            }
          }
        }
      }
  } else {
#pragma unroll
    for (int mt = 0; mt < 2; mt++) {
      float part[4] = {0.f, 0.f, 0.f, 0.f};
#pragma unroll
      for (int nt = 0; nt < 4; nt++) {
        int col = colBase + nt * 16 + l16;
        float wmv = Wm2[col];
#pragma unroll
        for (int r = 0; r < 4; r++) {
          int lr = wm + mt * 16 + quad * 4 + r;
          int ap = ap_s[lr];
          float tv = fmaxf(acc[mt][nt][r] + pc[ap * 256 + col], 0.f);
          part[r] += tv * wmv;
        }
      }
#pragma unroll
      for (int r = 0; r < 4; r++) {
#pragma unroll
        for (int off = 1; off < 16; off <<= 1) part[r] += __shfl_xor(part[r], off, 64);
        if (l16 == 0) {
          int row = rowBase + wm + mt * 16 + quad * 4 + r;
          if (row < Nn) atomicAdd(&prob[row], part[r]);
        }
      }
    }
  }
}

// ---------- pooling ----------
__global__ void k_pool(const float* __restrict__ h, const int* __restrict__ goff,
                       float* __restrict__ gout, float* __restrict__ gout2) {
  int g = blockIdx.x, c = threadIdx.x;
  int beg = goff[g], end = goff[g + 1];
  float s = 0.f;
  for (int n = beg; n < end; ++n) s += h[(size_t)n * Dd + c];
  gout[g * Dd + c] = s;
  if (gout2 != nullptr) gout2[g * Dd + c] = s;
}

// ---------- proto_contrib + proto norms ----------
__global__ void k_pc(const float* __restrict__ proto, const float* __restrict__ Wm1,
                     const float* __restrict__ bm1, float* __restrict__ pc,
                     float* __restrict__ pnorm) {
  int p = blockIdx.x, c = threadIdx.x;
  float s = bm1[c];
  for (int k = 0; k < Dd; k++) s += proto[p * Dd + k] * Wm1[(size_t)(Dd + k) * Dd + c];
  pc[p * Dd + c] = s;
  __shared__ float redn[256];
  float v = proto[p * Dd + c];
  redn[c] = v * v;
  __syncthreads();
  for (int off = 128; off > 0; off >>= 1) {
    if (c < off) redn[c] += redn[c + off];
    __syncthreads();
  }
  if (c == 0) {
    float n = sqrtf(redn[0]);
    pnorm[p] = (n == 0.f) ? EPSf : n;
  }
}

// ---------- cosine argmax (pass 1) ----------
__global__ __launch_bounds__(64) void k_assign(const float* __restrict__ ge,
                                               const float* __restrict__ proto,
                                               const float* __restrict__ pnorm,
                                               int* __restrict__ assign) {
  int g = blockIdx.x, lane = threadIdx.x;
  float4 v = *(const float4*)(ge + (size_t)g * Dd + lane * 4);
  float na = sqrtf(waveSum(v.x * v.x + v.y * v.y + v.z * v.z + v.w * v.w));
  if (na == 0.f) na = EPSf;
  float best = -1e30f;
  int bi = 0;
#pragma unroll
  for (int p = 0; p < Pp; p++) {
    float4 w = *(const float4*)(proto + (size_t)p * Dd + lane * 4);
    float d = waveSum(v.x * w.x + v.y * w.y + v.z * w.z + v.w * w.w);
    float sim = d / (na * pnorm[p]);
    if (sim > best) { best = sim; bi = p; }
  }
  if (lane == 0) assign[g] = bi;
}

// ---------- similarity + NCE (pass 2) ----------
__global__ __launch_bounds__(64) void k_simnce(const float* __restrict__ se,
                                               const float* __restrict__ proto,
                                               const float* __restrict__ pnorm,
                                               float* __restrict__ osim,
                                               float* __restrict__ snorm,
                                               float* __restrict__ nceAcc) {
  int g = blockIdx.x, lane = threadIdx.x;
  float4 v = *(const float4*)(se + (size_t)g * Dd + lane * 4);
  float na = sqrtf(waveSum(v.x * v.x + v.y * v.y + v.z * v.z + v.w * v.w));
  if (na == 0.f) na = EPSf;
  float sims[Pp];
#pragma unroll
  for (int p = 0; p < Pp; p++) {
    float4 w = *(const float4*)(proto + (size_t)p * Dd + lane * 4);
    float d = waveSum(v.x * w.x + v.y * w.y + v.z * w.z + v.w * w.w);
    float sim = d / (na * pnorm[p]);
    sims[p] = sim;
    if (lane == p) osim[g * Pp + p] = sim;
  }
  float best = sims[0];
  int bi = 0;
#pragma unroll
  for (int p = 1; p < Pp; p++) {
    if (sims[p] > best) { best = sims[p]; bi = p; }
  }
  float pos = 0.f, neg = 0.f;
#pragma unroll
  for (int p = 0; p < Pp; p++) {
    float e = expf(sims[p] / TEMPf);
    if (p == bi) pos = e; else neg += e;
  }
  float lg = -logf(pos / neg);
  if (lane == 0) {
    atomicAdd(nceAcc, lg);
    snorm[g] = na;
  }
}

// ---------- node_bern / edge_bern ----------
__global__ void k_bern(const float* __restrict__ prob, const float* __restrict__ bm2,
                       float* __restrict__ ob) {
  int i = blockIdx.x * 256 + threadIdx.x;
  if (i < Nn) {
    float z = prob[i] + bm2[0];
    ob[i] = 1.f / (1.f + expf(-z));
  }
}

__global__ void k_eb(const int* __restrict__ src, const int* __restrict__ dst,
                     const float* __restrict__ nb, float* __restrict__ oe) {
  int e = blockIdx.x * 256 + threadIdx.x;
  if (e < Ee) oe[e] = nb[src[e]] * nb[dst[e]];
}

// ---------- KL reduction ----------
__global__ void k_kl(const float* __restrict__ v, int n, float invA, float invB,
                     float* __restrict__ acc) {
  int i = blockIdx.x * 256 + threadIdx.x;
  float val = 0.f;
  if (i < n) {
    float xv = v[i];
    val = xv * logf(xv * invA + EPSf) + (1.f - xv) * logf((1.f - xv) * invB + EPSf);
  }
  val = waveSum(val);
  __shared__ float wsum[4];
  int lane = threadIdx.x & 63, wvv = threadIdx.x >> 6;
  if (lane == 0) wsum[wvv] = val;
  __syncthreads();
  if (threadIdx.x == 0) atomicAdd(acc, wsum[0] + wsum[1] + wsum[2] + wsum[3]);
}

__global__ void k_fin(const float* __restrict__ accs, float* __restrict__ o_kl,
                      float* __restrict__ o_nce) {
  o_kl[0] = accs[0] / (float)Nn + accs[1] / (float)Ee;
  o_nce[0] = accs[2] / (float)Gg;
}

// ---------- data_sim ----------
__global__ void k_datasim(const float* __restrict__ S, const float* __restrict__ snorm,
                          float* __restrict__ out) {
  __shared__ float si[Dd];
  int i = blockIdx.x, j = threadIdx.x;
  si[j] = S[(size_t)i * Dd + j];
  __syncthreads();
  const float4* rj = (const float4*)(S + (size_t)j * Dd);
  const float4* sif = (const float4*)si;
  float d = 0.f;
#pragma unroll 4
  for (int k = 0; k < Dd / 4; k++) {
    float4 a = sif[k];
    float4 b = rj[k];
    d += a.x * b.x + a.y * b.y + a.z * b.z + a.w * b.w;
  }
  out[(size_t)i * Gg + j] = d / (snorm[i] * snorm[j]);
}

// ---------- weight split/transpose + x->bf16 ----------
__global__ void k_splitw(const float* __restrict__ W, u16* __restrict__ th,
                         u16* __restrict__ tl, int K) {
  int idx = blockIdx.x * 256 + threadIdx.x;
  if (idx >= K * 256) return;
  int k = idx >> 8, n = idx & 255;
  float v = W[idx];
  u16 h = f2bf(v);
  th[(size_t)n * K + k] = h;
  tl[(size_t)n * K + k] = f2bf(v - bf2f(h));
}

__global__ void k_cvtbf(const float* __restrict__ x, u16* __restrict__ o, int n) {
  int i = blockIdx.x * 256 + threadIdx.x;
  if (i < n) o[i] = f2bf(x[i]);
}

}  // namespace

extern "C" void kernel_launch(void* const* d_in, const int* in_sizes, int n_in,
                              void* d_out, int out_size, void* d_ws, size_t ws_size,
                              hipStream_t stream) {
  const float* x = (const float*)d_in[0];
  const int* ei = (const int*)d_in[1];
  const int* batch = (const int*)d_in[2];
  const float* W1 = (const float*)d_in[3];
  const float* b1 = (const float*)d_in[4];
  const float* W2 = (const float*)d_in[5];
  const float* b2 = (const float*)d_in[6];
  const float* Wm1 = (const float*)d_in[7];
  const float* bm1 = (const float*)d_in[8];
  const float* Wm2 = (const float*)d_in[9];
  const float* bm2 = (const float*)d_in[10];
  const float* proto = (const float*)d_in[11];
  const int* src = ei;
  const int* dst = ei + Ee;

  float* out = (float*)d_out;
  float* o_kl = out;
  float* o_nce = out + 1;
  float* o_sim = out + 2;
  float* o_nb = o_sim + Gg * Pp;
  float* o_eb = o_nb + Nn;
  float* o_ds = o_eb + Ee;
  float* o_sg = o_ds + Gg * Gg;
  float* o_ne = o_sg + Gg * Dd;

  char* w = (char*)d_ws;
  auto take = [&](size_t bytes) -> char* {
    char* p = w;
    w += (bytes + 255) & ~(size_t)255;
    return p;
  };
  const size_t halfR = (size_t)Npad * 256 * 2;  // one bf16 [Npad][256] array
  // R1: f32 [Npad][256] (h1 in pass1, h2b in pass2)
  float* bufB = (float*)take((size_t)Npad * 256 * 4);
  // R2: pass1: A1h|A1l (each [Npad][128]) then A2h|A2l (each [Npad][256]);
  //     pass2: h1b (bf16 [Npad][256]) | a2bh ([Npad][256])
  char* R2 = take(2 * halfR);
  u16* A1h = (u16*)R2;
  u16* A1l = (u16*)(R2 + (size_t)Npad * 128 * 2);
  u16* A2h = (u16*)R2;
  u16* A2l = (u16*)(R2 + halfR);
  u16* h1b = (u16*)R2;
  u16* a2bh = (u16*)(R2 + halfR);
  // R3: pass1: ne_h | ne_l; pass2: a1bh ([Npad][128]) | xbf ([Nn][128])
  char* R3 = take(2 * halfR);
  u16* neh = (u16*)R3;
  u16* nel = (u16*)(R3 + halfR);
  u16* a1bh = (u16*)R3;
  u16* xbf = (u16*)(R3 + halfR);

  int* csr = (int*)take((size_t)Ee * 4);
  int* deg = (int*)take((size_t)Nn * 4);
  int* cursor = (int*)take((size_t)Nn * 4);
  int* offs = (int*)take((size_t)(Nn + 1) * 4);
  int* goff = (int*)take((size_t)(Gg + 1) * 4);
  float* gemb = (float*)take((size_t)Gg * Dd * 4);
  float* sgemb = (float*)take((size_t)Gg * Dd * 4);
  float* pcb = (float*)take((size_t)Pp * Dd * 4);
  float* pnorm = (float*)take(Pp * 4);
  int* assign = (int*)take(Gg * 4);
  float* snorm = (float*)take(Gg * 4);
  float* prob = (float*)take(Nn * 4);
  float* accs = (float*)take(16);
  u16* W1th = (u16*)take((size_t)256 * 128 * 2);
  u16* W1tl = (u16*)take((size_t)256 * 128 * 2);
  u16* W2th = (u16*)take((size_t)256 * 256 * 2);
  u16* W2tl = (u16*)take((size_t)256 * 256 * 2);
  u16* Wm1th = (u16*)take((size_t)256 * 256 * 2);
  u16* Wm1tl = (u16*)take((size_t)256 * 256 * 2);

  hipMemsetAsync(deg, 0, Nn * 4, stream);
  hipMemsetAsync(cursor, 0, Nn * 4, stream);
  hipMemsetAsync(prob, 0, Nn * 4, stream);
  hipMemsetAsync(accs, 0, 16, stream);

  const int eB = (Ee + 255) / 256;
  const int nB = (Nn + 255) / 256;
  const int aggB = (Nn * 64 + 255) / 256;
  dim3 gmm(4, 157);  // 64-col x 128-row tiles

  k_deg<<<eB, 256, 0, stream>>>(dst, deg);
  k_scan<<<1, 1024, 0, stream>>>(deg, offs);
  k_fill<<<eB, 256, 0, stream>>>(src, dst, offs, cursor, csr);
  k_goff<<<nB, 256, 0, stream>>>(batch, goff);
  k_pc<<<Pp, 256, 0, stream>>>(proto, Wm1, bm1, pcb, pnorm);
  k_splitw<<<(128 * 256 + 255) / 256, 256, 0, stream>>>(W1, W1th, W1tl, 128);
  k_splitw<<<(256 * 256 + 255) / 256, 256, 0, stream>>>(W2, W2th, W2tl, 256);
  k_splitw<<<(256 * 256 + 255) / 256, 256, 0, stream>>>(Wm1, Wm1th, Wm1tl, 256);

  // ---- pass 1 (split-bf16 GEMMs, f32 gathers) ----
  k_agg<128, 0, false, true><<<aggB, 256, 0, stream>>>(x, nullptr, offs, csr, A1h, A1l);
  k_mm<128, true, 0><<<gmm, 256, 0, stream>>>(A1h, A1l, W1th, W1tl, b1, bufB, nullptr,
                                              nullptr, nullptr, nullptr, nullptr,
                                              nullptr, nullptr);
  k_agg<256, 0, false, true><<<aggB, 256, 0, stream>>>(bufB, nullptr, offs, csr, A2h, A2l);
  k_mm<256, true, 0><<<gmm, 256, 0, stream>>>(A2h, A2l, W2th, W2tl, b2, o_ne, neh, nel,
                                              nullptr, nullptr, nullptr, nullptr,
                                              nullptr);
  k_pool<<<Gg, 256, 0, stream>>>(o_ne, goff, gemb, nullptr);
  k_assign<<<Gg, 64, 0, stream>>>(gemb, proto, pnorm, assign);
  k_mm<256, true, 1><<<gmm, 256, 0, stream>>>(neh, nel, Wm1th, Wm1tl, nullptr, nullptr,
                                              nullptr, nullptr, pcb, batch, assign,
                                              Wm2, prob);
  k_bern<<<nB, 256, 0, stream>>>(prob, bm2, o_nb);
  k_eb<<<eB, 256, 0, stream>>>(src, dst, o_nb, o_eb);

  // ---- pass 2 (plain bf16 GEMMs, bf16 gathers) ----
  k_cvtbf<<<(Nn * 128 + 255) / 256, 256, 0, stream>>>(x, xbf, Nn * 128);
  k_agg<128, 1, true, false><<<aggB, 256, 0, stream>>>(xbf, o_nb, offs, csr, a1bh, nullptr);
  k_mm<128, false, 0><<<gmm, 256, 0, stream>>>(a1bh, nullptr, W1th, nullptr, b1, nullptr,
                                               h1b, nullptr, nullptr, nullptr, nullptr,
                                               nullptr, nullptr);
  k_agg<256, 2, true, false><<<aggB, 256, 0, stream>>>(h1b, o_nb, offs, csr, a2bh, nullptr);
  k_mm<256, false, 0><<<gmm, 256, 0, stream>>>(a2bh, nullptr, W2th, nullptr, b2, bufB,
                                               nullptr, nullptr, nullptr, nullptr,
                                               nullptr, nullptr, nullptr);
  k_pool<<<Gg, 256, 0, stream>>>(bufB, goff, sgemb, o_sg);

  k_simnce<<<Gg, 64, 0, stream>>>(sgemb, proto, pnorm, o_sim, snorm, accs + 2);
  k_kl<<<nB, 256, 0, stream>>>(o_nb, Nn, 1.f / Rf, 1.f / (1.f - Rf + EPSf), accs + 0);
  k_kl<<<eB, 256, 0, stream>>>(o_eb, Ee, 1.f / (Rf * Rf), 1.f / (1.f - Rf * Rf + EPSf),
                               accs + 1);
  k_fin<<<1, 1, 0, stream>>>(accs, o_kl, o_nce);
  k_datasim<<<Gg, 256, 0, stream>>>(sgemb, snorm, o_ds);
}

// Round 4
// 473.297 us; speedup vs baseline: 1.3272x; 1.0335x over previous
//
#include <hip/hip_runtime.h>
#include <cmath>
#include <cstdint>

#define DINL __device__ __forceinline__

namespace {

constexpr int Nn = 20000, Ee = 320000, Gg = 256, Dd = 256, Pp = 16;
constexpr int Npad = 20096;  // 157 * 128
constexpr float EPSf = 1e-7f, Rf = 0.5f, TEMPf = 0.2f;

typedef unsigned short u16;
typedef __attribute__((ext_vector_type(8))) short short8;
typedef __attribute__((ext_vector_type(4))) float floatx4;

DINL float waveSum(float x) {
#pragma unroll
  for (int off = 32; off > 0; off >>= 1) x += __shfl_xor(x, off, 64);
  return x;
}

DINL u16 f2bf(float f) {
  unsigned u = __float_as_uint(f);
  unsigned r = u + 0x7fffu + ((u >> 16) & 1u);
  return (u16)(r >> 16);
}
DINL float bf2f(u16 h) { return __uint_as_float(((unsigned)h) << 16); }

// ---------- CSR build ----------
__global__ void k_deg(const int* __restrict__ dst, int* __restrict__ deg) {
  int e = blockIdx.x * 256 + threadIdx.x;
  if (e < Ee) atomicAdd(&deg[dst[e]], 1);
}

__global__ __launch_bounds__(1024) void k_scan(const int* __restrict__ deg,
                                               int* __restrict__ offs) {
  __shared__ int part[1024];
  int tid = threadIdx.x;
  const int chunk = (Nn + 1023) >> 10;
  int start = tid * chunk;
  int s = 0;
  for (int k = 0; k < chunk; k++) { int i = start + k; if (i < Nn) s += deg[i]; }
  part[tid] = s;
  __syncthreads();
  for (int off = 1; off < 1024; off <<= 1) {
    int v = (tid >= off) ? part[tid - off] : 0;
    __syncthreads();
    part[tid] += v;
    __syncthreads();
  }
  int run = (tid == 0) ? 0 : part[tid - 1];
  for (int k = 0; k < chunk; k++) {
    int i = start + k;
    if (i < Nn) { offs[i] = run; run += deg[i]; }
  }
  if (start < Nn && start + chunk >= Nn) offs[Nn] = run;
}

__global__ void k_fill(const int* __restrict__ src, const int* __restrict__ dst,
                       const int* __restrict__ offs, int* __restrict__ cursor,
                       int* __restrict__ csr) {
  int e = blockIdx.x * 256 + threadIdx.x;
  if (e < Ee) {
    int d = dst[e];
    int pos = atomicAdd(&cursor[d], 1);
    csr[offs[d] + pos] = src[e];
  }
}

__global__ void k_goff(const int* __restrict__ batch, int* __restrict__ goff) {
  int i = blockIdx.x * 256 + threadIdx.x;
  if (i >= Nn) return;
  int bi = batch[i];
  int bp = (i == 0) ? -1 : batch[i - 1];
  for (int g = bp + 1; g <= bi; ++g) goff[g] = i;
  if (i == Nn - 1)
    for (int g = bi + 1; g <= Gg; ++g) goff[g] = Nn;
}

// ---------- 128B row-slice loader ----------
template <int DIM, int EPL, bool INBF>
DINL void slice(float r[EPL], const void* __restrict__ hv, int row, int ce) {
  if constexpr (INBF) {
    const u16* p = (const u16*)hv + (size_t)row * DIM + ce;
    ushort4 u = *(const ushort4*)p;
    r[0] = bf2f(u.x); r[1] = bf2f(u.y); r[2] = bf2f(u.z); r[3] = bf2f(u.w);
  } else {
    const float* p = (const float*)hv + (size_t)row * DIM + ce;
    float2 u = *(const float2*)p;
    r[0] = u.x; r[1] = u.y;
  }
}

// ---------- chunked edge aggregation ----------
// Column-chunked so each XCD's gathers stay within a 2.5MB slice of h (fits
// 4MB per-XCD L2). chunk = blockIdx.x % CHUNKS  <-> round-robin XCD dispatch.
// 16 lanes per node (8B/lane = 128B slice), 4 nodes per wave.
// MODE 0: v = h[i] + sum_s h[s]                       (-> split hi/lo out)
// MODE 1: v = nb[i]*( h[i] + sum_s h[s]*nb[s]^2 )     (-> hi out)
// MODE 2: v = h[i] + nb[i]*sum_s h[s]*nb[s]           (-> hi out)
template <int DIM, int MODE, bool INBF, bool OSPL>
__global__ __launch_bounds__(256) void k_aggc(
    const void* __restrict__ hv, const float* __restrict__ nb,
    const int* __restrict__ offs, const int* __restrict__ csr,
    u16* __restrict__ oh, u16* __restrict__ ol) {
  constexpr int EPL = INBF ? 4 : 2;
  constexpr int COLS = EPL * 16;
  constexpr int CHUNKS = DIM / COLS;
  int c = (int)(blockIdx.x % CHUNKS);
  int grp = (int)(blockIdx.x / CHUNKS);
  int wv = threadIdx.x >> 6, lane = threadIdx.x & 63;
  int sub = lane >> 4, l = lane & 15;
  int node = grp * 16 + wv * 4 + sub;
  if (node >= Nn) return;
  int ce = c * COLS + l * EPL;
  float self[EPL], ts[EPL];
  slice<DIM, EPL, INBF>(self, hv, node, ce);
#pragma unroll
  for (int j = 0; j < EPL; j++) ts[j] = 0.f;
  int beg = offs[node], end = offs[node + 1];
  int k = beg;
  for (; k + 4 <= end; k += 4) {
    int s0 = csr[k], s1 = csr[k + 1], s2 = csr[k + 2], s3 = csr[k + 3];
    float r0[EPL], r1[EPL], r2[EPL], r3[EPL];
    slice<DIM, EPL, INBF>(r0, hv, s0, ce);
    slice<DIM, EPL, INBF>(r1, hv, s1, ce);
    slice<DIM, EPL, INBF>(r2, hv, s2, ce);
    slice<DIM, EPL, INBF>(r3, hv, s3, ce);
    if (MODE == 0) {
#pragma unroll
      for (int j = 0; j < EPL; j++) ts[j] += (r0[j] + r1[j]) + (r2[j] + r3[j]);
    } else {
      float w0 = nb[s0], w1 = nb[s1], w2 = nb[s2], w3 = nb[s3];
      if (MODE == 1) { w0 *= w0; w1 *= w1; w2 *= w2; w3 *= w3; }
#pragma unroll
      for (int j = 0; j < EPL; j++)
        ts[j] += (w0 * r0[j] + w1 * r1[j]) + (w2 * r2[j] + w3 * r3[j]);
    }
  }
  for (; k < end; k++) {
    int s = csr[k];
    float r[EPL];
    slice<DIM, EPL, INBF>(r, hv, s, ce);
    if (MODE == 0) {
#pragma unroll
      for (int j = 0; j < EPL; j++) ts[j] += r[j];
    } else {
      float wq = nb[s];
      if (MODE == 1) wq *= wq;
#pragma unroll
      for (int j = 0; j < EPL; j++) ts[j] += wq * r[j];
    }
  }
  float val[EPL];
  if (MODE == 0) {
#pragma unroll
    for (int j = 0; j < EPL; j++) val[j] = self[j] + ts[j];
  } else if (MODE == 1) {
    float wi = nb[node];
#pragma unroll
    for (int j = 0; j < EPL; j++) val[j] = wi * (self[j] + ts[j]);
  } else {
    float wi = nb[node];
#pragma unroll
    for (int j = 0; j < EPL; j++) val[j] = self[j] + wi * ts[j];
  }
  u16 hs[EPL], ls[EPL];
#pragma unroll
  for (int j = 0; j < EPL; j++) {
    hs[j] = f2bf(val[j]);
    if (OSPL) ls[j] = f2bf(val[j] - bf2f(hs[j]));
  }
  u16* po = oh + (size_t)node * DIM + ce;
  if constexpr (EPL == 2) {
    *(ushort2*)po = make_ushort2(hs[0], hs[1]);
  } else {
    *(ushort4*)po = make_ushort4(hs[0], hs[1], hs[2], hs[3]);
  }
  if constexpr (OSPL) {
    u16* pl = ol + (size_t)node * DIM + ce;
    if constexpr (EPL == 2) {
      *(ushort2*)pl = make_ushort2(ls[0], ls[1]);
    } else {
      *(ushort4*)pl = make_ushort4(ls[0], ls[1], ls[2], ls[3]);
    }
  }
}

// ---------- MFMA GEMM: C[M,256] = A[M,K] @ B[K,256], A/Bt pre-split bf16 ----------
template <int K, bool SPLIT, int MODE>
__global__ __launch_bounds__(256) void k_mm(
    const u16* __restrict__ Ah, const u16* __restrict__ Al,
    const u16* __restrict__ Bh, const u16* __restrict__ Bl,
    const float* __restrict__ bias,
    float* __restrict__ outF, u16* __restrict__ outH, u16* __restrict__ outL,
    const float* __restrict__ pc, const int* __restrict__ batch,
    const int* __restrict__ assign, const float* __restrict__ Wm2,
    float* __restrict__ prob) {
  constexpr int SK = 40;
  __shared__ u16 AsH[128 * SK];
  __shared__ u16 AsL[SPLIT ? 128 * SK : 16];
  __shared__ u16 BsH[64 * SK];
  __shared__ u16 BsL[SPLIT ? 64 * SK : 16];
  __shared__ int ap_s[128];
  int t = threadIdx.x;
  int rowBase = blockIdx.y * 128, colBase = blockIdx.x * 64;
  if (MODE == 1 && t < 128) {
    int r = rowBase + t;
    ap_s[t] = (r < Nn) ? assign[batch[r]] : 0;
  }
  int lane = t & 63, wv = t >> 6;
  int quad = lane >> 4, l16 = lane & 15;
  int wm = wv * 32;
  floatx4 acc[2][4];
#pragma unroll
  for (int mt = 0; mt < 2; mt++)
#pragma unroll
    for (int nt = 0; nt < 4; nt++) acc[mt][nt] = (floatx4){0.f, 0.f, 0.f, 0.f};

  int ar = t >> 1;
  int akh = (t & 1) * 16;
  const u16* agH = Ah + (size_t)(rowBase + ar) * K + akh;
  const u16* agL = Al + (size_t)(rowBase + ar) * K + akh;
  int bn = t >> 2;
  int bko = (t & 3) * 8;
  const u16* bgH = Bh + (size_t)(colBase + bn) * K + bko;
  const u16* bgL = Bl + (size_t)(colBase + bn) * K + bko;

  for (int k0 = 0; k0 < K; k0 += 32) {
    uint4 a0 = *(const uint4*)(agH + k0);
    uint4 a1 = *(const uint4*)(agH + k0 + 8);
    uint4 b0 = *(const uint4*)(bgH + k0);
    uint4 a0l, a1l, b0l;
    if constexpr (SPLIT) {
      a0l = *(const uint4*)(agL + k0);
      a1l = *(const uint4*)(agL + k0 + 8);
      b0l = *(const uint4*)(bgL + k0);
    }
    __syncthreads();
    *(uint4*)&AsH[ar * SK + akh] = a0;
    *(uint4*)&AsH[ar * SK + akh + 8] = a1;
    *(uint4*)&BsH[bn * SK + bko] = b0;
    if constexpr (SPLIT) {
      *(uint4*)&AsL[ar * SK + akh] = a0l;
      *(uint4*)&AsL[ar * SK + akh + 8] = a1l;
      *(uint4*)&BsL[bn * SK + bko] = b0l;
    }
    __syncthreads();
    short8 aH[2], aL[2], bH[4], bL[4];
#pragma unroll
    for (int mt = 0; mt < 2; mt++) {
      int off = (wm + mt * 16 + l16) * SK + quad * 8;
      aH[mt] = *(const short8*)&AsH[off];
      if (SPLIT) aL[mt] = *(const short8*)&AsL[off];
    }
#pragma unroll
    for (int nt = 0; nt < 4; nt++) {
      int off = (nt * 16 + l16) * SK + quad * 8;
      bH[nt] = *(const short8*)&BsH[off];
      if (SPLIT) bL[nt] = *(const short8*)&BsL[off];
    }
#pragma unroll
    for (int mt = 0; mt < 2; mt++)
#pragma unroll
      for (int nt = 0; nt < 4; nt++) {
        acc[mt][nt] = __builtin_amdgcn_mfma_f32_16x16x32_bf16(aH[mt], bH[nt], acc[mt][nt], 0, 0, 0);
        if constexpr (SPLIT) {
          acc[mt][nt] = __builtin_amdgcn_mfma_f32_16x16x32_bf16(aH[mt], bL[nt], acc[mt][nt], 0, 0, 0);
          acc[mt][nt] = __builtin_amdgcn_mfma_f32_16x16x32_bf16(aL[mt], bH[nt], acc[mt][nt], 0, 0, 0);
        }
      }
  }

  if constexpr (MODE == 0) {
#pragma unroll
    for (int mt = 0; mt < 2; mt++)
#pragma unroll
      for (int nt = 0; nt < 4; nt++) {
        int col = colBase + nt * 16 + l16;
        float bv = bias[col];
#pragma unroll
        for (int r = 0; r < 4; r++) {
          int row = rowBase + wm + mt * 16 + quad * 4 + r;
          if (row < Nn) {
            float v = fmaxf(acc[mt][nt][r] + bv, 0.f);
            size_t o = (size_t)row * 256 + col;
            if (outF) outF[o] = v;
            if (outH) {
              u16 hh = f2bf(v);
              outH[o] = hh;
              if (outL) outL[o] = f2bf(v - bf2f(hh));
            }
          }
        }
      }
  } else {
#pragma unroll
    for (int mt = 0; mt < 2; mt++) {
      float part[4] = {0.f, 0.f, 0.f, 0.f};
#pragma unroll
      for (int nt = 0; nt < 4; nt++) {
        int col = colBase + nt * 16 + l16;
        float wmv = Wm2[col];
#pragma unroll
        for (int r = 0; r < 4; r++) {
          int lr = wm + mt * 16 + quad * 4 + r;
          int ap = ap_s[lr];
          float tv = fmaxf(acc[mt][nt][r] + pc[ap * 256 + col], 0.f);
          part[r] += tv * wmv;
        }
      }
#pragma unroll
      for (int r = 0; r < 4; r++) {
#pragma unroll
        for (int off = 1; off < 16; off <<= 1) part[r] += __shfl_xor(part[r], off, 64);
        if (l16 == 0) {
          int row = rowBase + wm + mt * 16 + quad * 4 + r;
          if (row < Nn) atomicAdd(&prob[row], part[r]);
        }
      }
    }
  }
}

// ---------- pooling: (graph, col-quarter) blocks ----------
__global__ __launch_bounds__(64) void k_pool(const float* __restrict__ h,
                                             const int* __restrict__ goff,
                                             float* __restrict__ gout,
                                             float* __restrict__ gout2) {
  int g = blockIdx.x, q = blockIdx.y, c = q * 64 + threadIdx.x;
  int beg = goff[g], end = goff[g + 1];
  float s = 0.f;
  for (int n = beg; n < end; ++n) s += h[(size_t)n * Dd + c];
  gout[g * Dd + c] = s;
  if (gout2 != nullptr) gout2[g * Dd + c] = s;
}

// ---------- proto_contrib + proto norms ----------
__global__ __launch_bounds__(64) void k_pc(const float* __restrict__ proto,
                                           const float* __restrict__ Wm1,
                                           const float* __restrict__ bm1,
                                           float* __restrict__ pc,
                                           float* __restrict__ pnorm) {
  int p = blockIdx.x, q = blockIdx.y, t = threadIdx.x;
  int cc = q * 64 + t;
  float s = bm1[cc];
  for (int k = 0; k < Dd; k++) s += proto[p * Dd + k] * Wm1[(size_t)(Dd + k) * Dd + cc];
  pc[p * Dd + cc] = s;
  if (q == 0) {
    float4 v = ((const float4*)(proto + (size_t)p * Dd))[t];
    float nsq = waveSum(v.x * v.x + v.y * v.y + v.z * v.z + v.w * v.w);
    if (t == 0) {
      float n = sqrtf(nsq);
      pnorm[p] = (n == 0.f) ? EPSf : n;
    }
  }
}

// ---------- cosine argmax (pass 1) ----------
__global__ __launch_bounds__(64) void k_assign(const float* __restrict__ ge,
                                               const float* __restrict__ proto,
                                               const float* __restrict__ pnorm,
                                               int* __restrict__ assign) {
  int g = blockIdx.x, lane = threadIdx.x;
  float4 v = *(const float4*)(ge + (size_t)g * Dd + lane * 4);
  float na = sqrtf(waveSum(v.x * v.x + v.y * v.y + v.z * v.z + v.w * v.w));
  if (na == 0.f) na = EPSf;
  float best = -1e30f;
  int bi = 0;
#pragma unroll
  for (int p = 0; p < Pp; p++) {
    float4 w = *(const float4*)(proto + (size_t)p * Dd + lane * 4);
    float d = waveSum(v.x * w.x + v.y * w.y + v.z * w.z + v.w * w.w);
    float sim = d / (na * pnorm[p]);
    if (sim > best) { best = sim; bi = p; }
  }
  if (lane == 0) assign[g] = bi;
}

// ---------- similarity + NCE (pass 2) ----------
__global__ __launch_bounds__(64) void k_simnce(const float* __restrict__ se,
                                               const float* __restrict__ proto,
                                               const float* __restrict__ pnorm,
                                               float* __restrict__ osim,
                                               float* __restrict__ snorm,
                                               float* __restrict__ nceAcc) {
  int g = blockIdx.x, lane = threadIdx.x;
  float4 v = *(const float4*)(se + (size_t)g * Dd + lane * 4);
  float na = sqrtf(waveSum(v.x * v.x + v.y * v.y + v.z * v.z + v.w * v.w));
  if (na == 0.f) na = EPSf;
  float sims[Pp];
#pragma unroll
  for (int p = 0; p < Pp; p++) {
    float4 w = *(const float4*)(proto + (size_t)p * Dd + lane * 4);
    float d = waveSum(v.x * w.x + v.y * w.y + v.z * w.z + v.w * w.w);
    float sim = d / (na * pnorm[p]);
    sims[p] = sim;
    if (lane == p) osim[g * Pp + p] = sim;
  }
  float best = sims[0];
  int bi = 0;
#pragma unroll
  for (int p = 1; p < Pp; p++) {
    if (sims[p] > best) { best = sims[p]; bi = p; }
  }
  float pos = 0.f, neg = 0.f;
#pragma unroll
  for (int p = 0; p < Pp; p++) {
    float e = expf(sims[p] / TEMPf);
    if (p == bi) pos = e; else neg += e;
  }
  float lg = -logf(pos / neg);
  if (lane == 0) {
    atomicAdd(nceAcc, lg);
    snorm[g] = na;
  }
}

// ---------- node_bern (+ node KL fused) ----------
__global__ void k_bern(const float* __restrict__ prob, const float* __restrict__ bm2,
                       float* __restrict__ ob, float* __restrict__ accs) {
  int i = blockIdx.x * 256 + threadIdx.x;
  float val = 0.f;
  if (i < Nn) {
    float z = prob[i] + bm2[0];
    float p = 1.f / (1.f + expf(-z));
    ob[i] = p;
    const float invA = 1.f / Rf, invB = 1.f / (1.f - Rf + EPSf);
    val = p * logf(p * invA + EPSf) + (1.f - p) * logf((1.f - p) * invB + EPSf);
  }
  val = waveSum(val);
  __shared__ float wsum[4];
  int lane = threadIdx.x & 63, wvv = threadIdx.x >> 6;
  if (lane == 0) wsum[wvv] = val;
  __syncthreads();
  if (threadIdx.x == 0) atomicAdd(accs, wsum[0] + wsum[1] + wsum[2] + wsum[3]);
}

// ---------- edge_bern (+ edge KL fused) ----------
__global__ void k_eb(const int* __restrict__ src, const int* __restrict__ dst,
                     const float* __restrict__ nb, float* __restrict__ oe,
                     float* __restrict__ accs) {
  int e = blockIdx.x * 256 + threadIdx.x;
  float val = 0.f;
  if (e < Ee) {
    float v = nb[src[e]] * nb[dst[e]];
    oe[e] = v;
    const float invA = 1.f / (Rf * Rf), invB = 1.f / (1.f - Rf * Rf + EPSf);
    val = v * logf(v * invA + EPSf) + (1.f - v) * logf((1.f - v) * invB + EPSf);
  }
  val = waveSum(val);
  __shared__ float wsum[4];
  int lane = threadIdx.x & 63, wvv = threadIdx.x >> 6;
  if (lane == 0) wsum[wvv] = val;
  __syncthreads();
  if (threadIdx.x == 0) atomicAdd(accs + 1, wsum[0] + wsum[1] + wsum[2] + wsum[3]);
}

__global__ void k_fin(const float* __restrict__ accs, float* __restrict__ o_kl,
                      float* __restrict__ o_nce) {
  o_kl[0] = accs[0] / (float)Nn + accs[1] / (float)Ee;
  o_nce[0] = accs[2] / (float)Gg;
}

// ---------- data_sim ----------
__global__ void k_datasim(const float* __restrict__ S, const float* __restrict__ snorm,
                          float* __restrict__ out) {
  __shared__ float si[Dd];
  int i = blockIdx.x, j = threadIdx.x;
  si[j] = S[(size_t)i * Dd + j];
  __syncthreads();
  const float4* rj = (const float4*)(S + (size_t)j * Dd);
  const float4* sif = (const float4*)si;
  float d = 0.f;
#pragma unroll 4
  for (int k = 0; k < Dd / 4; k++) {
    float4 a = sif[k];
    float4 b = rj[k];
    d += a.x * b.x + a.y * b.y + a.z * b.z + a.w * b.w;
  }
  out[(size_t)i * Gg + j] = d / (snorm[i] * snorm[j]);
}

// ---------- weight split/transpose + x->bf16 ----------
__global__ void k_splitw(const float* __restrict__ W, u16* __restrict__ th,
                         u16* __restrict__ tl, int K) {
  int idx = blockIdx.x * 256 + threadIdx.x;
  if (idx >= K * 256) return;
  int k = idx >> 8, n = idx & 255;
  float v = W[idx];
  u16 h = f2bf(v);
  th[(size_t)n * K + k] = h;
  tl[(size_t)n * K + k] = f2bf(v - bf2f(h));
}

__global__ void k_cvtbf4(const float4* __restrict__ x, ushort4* __restrict__ o, int n4) {
  int i = blockIdx.x * 256 + threadIdx.x;
  if (i < n4) {
    float4 v = x[i];
    o[i] = make_ushort4(f2bf(v.x), f2bf(v.y), f2bf(v.z), f2bf(v.w));
  }
}

}  // namespace

extern "C" void kernel_launch(void* const* d_in, const int* in_sizes, int n_in,
                              void* d_out, int out_size, void* d_ws, size_t ws_size,
                              hipStream_t stream) {
  const float* x = (const float*)d_in[0];
  const int* ei = (const int*)d_in[1];
  const int* batch = (const int*)d_in[2];
  const float* W1 = (const float*)d_in[3];
  const float* b1 = (const float*)d_in[4];
  const float* W2 = (const float*)d_in[5];
  const float* b2 = (const float*)d_in[6];
  const float* Wm1 = (const float*)d_in[7];
  const float* bm1 = (const float*)d_in[8];
  const float* Wm2 = (const float*)d_in[9];
  const float* bm2 = (const float*)d_in[10];
  const float* proto = (const float*)d_in[11];
  const int* src = ei;
  const int* dst = ei + Ee;

  float* out = (float*)d_out;
  float* o_kl = out;
  float* o_nce = out + 1;
  float* o_sim = out + 2;
  float* o_nb = o_sim + Gg * Pp;
  float* o_eb = o_nb + Nn;
  float* o_ds = o_eb + Ee;
  float* o_sg = o_ds + Gg * Gg;
  float* o_ne = o_sg + Gg * Dd;

  char* w = (char*)d_ws;
  auto take = [&](size_t bytes) -> char* {
    char* p = w;
    w += (bytes + 255) & ~(size_t)255;
    return p;
  };
  const size_t halfR = (size_t)Npad * 256 * 2;
  float* bufB = (float*)take((size_t)Npad * 256 * 4);
  char* R2 = take(2 * halfR);
  u16* A1h = (u16*)R2;
  u16* A1l = (u16*)(R2 + (size_t)Npad * 128 * 2);
  u16* A2h = (u16*)R2;
  u16* A2l = (u16*)(R2 + halfR);
  u16* h1b = (u16*)R2;
  u16* a2bh = (u16*)(R2 + halfR);
  // R3 aliasing: neh|nel (pass 1)  then  a1bh|xbf (pass 2).
  // CAUTION: xbf aliases nel -> the x->bf16 conversion MUST run after the
  // masker GEMM (last consumer of nel). Moving it earlier was R3's bug.
  char* R3 = take(2 * halfR);
  u16* neh = (u16*)R3;
  u16* nel = (u16*)(R3 + halfR);
  u16* a1bh = (u16*)R3;
  u16* xbf = (u16*)(R3 + halfR);

  int* csr = (int*)take((size_t)Ee * 4);
  int* deg = (int*)take((size_t)Nn * 4);
  int* cursor = (int*)take((size_t)Nn * 4);
  int* offs = (int*)take((size_t)(Nn + 1) * 4);
  int* goff = (int*)take((size_t)(Gg + 1) * 4);
  float* gemb = (float*)take((size_t)Gg * Dd * 4);
  float* sgemb = (float*)take((size_t)Gg * Dd * 4);
  float* pcb = (float*)take((size_t)Pp * Dd * 4);
  float* pnorm = (float*)take(Pp * 4);
  int* assign = (int*)take(Gg * 4);
  float* snorm = (float*)take(Gg * 4);
  float* prob = (float*)take(Nn * 4);
  float* accs = (float*)take(16);
  u16* W1th = (u16*)take((size_t)256 * 128 * 2);
  u16* W1tl = (u16*)take((size_t)256 * 128 * 2);
  u16* W2th = (u16*)take((size_t)256 * 256 * 2);
  u16* W2tl = (u16*)take((size_t)256 * 256 * 2);
  u16* Wm1th = (u16*)take((size_t)256 * 256 * 2);
  u16* Wm1tl = (u16*)take((size_t)256 * 256 * 2);

  // deg+cursor are adjacent 80128B-aligned blocks; prob(80128) then accs.
  hipMemsetAsync(deg, 0, 2 * 80128, stream);
  hipMemsetAsync(prob, 0, 80128 + 16, stream);

  const int eB = (Ee + 255) / 256;
  const int nB = (Nn + 255) / 256;
  dim3 gmm(4, 157);

  k_deg<<<eB, 256, 0, stream>>>(dst, deg);
  k_scan<<<1, 1024, 0, stream>>>(deg, offs);
  k_fill<<<eB, 256, 0, stream>>>(src, dst, offs, cursor, csr);
  k_goff<<<nB, 256, 0, stream>>>(batch, goff);
  k_pc<<<dim3(Pp, 4), 64, 0, stream>>>(proto, Wm1, bm1, pcb, pnorm);
  k_splitw<<<(128 * 256 + 255) / 256, 256, 0, stream>>>(W1, W1th, W1tl, 128);
  k_splitw<<<(256 * 256 + 255) / 256, 256, 0, stream>>>(W2, W2th, W2tl, 256);
  k_splitw<<<(256 * 256 + 255) / 256, 256, 0, stream>>>(Wm1, Wm1th, Wm1tl, 256);

  // ---- pass 1 (split-bf16 GEMMs, f32 chunked gathers) ----
  k_aggc<128, 0, false, true><<<1250 * 4, 256, 0, stream>>>(x, nullptr, offs, csr, A1h, A1l);
  k_mm<128, true, 0><<<gmm, 256, 0, stream>>>(A1h, A1l, W1th, W1tl, b1, bufB, nullptr,
                                              nullptr, nullptr, nullptr, nullptr,
                                              nullptr, nullptr);
  k_aggc<256, 0, false, true><<<1250 * 8, 256, 0, stream>>>(bufB, nullptr, offs, csr, A2h, A2l);
  k_mm<256, true, 0><<<gmm, 256, 0, stream>>>(A2h, A2l, W2th, W2tl, b2, o_ne, neh, nel,
                                              nullptr, nullptr, nullptr, nullptr,
                                              nullptr);
  k_pool<<<dim3(Gg, 4), 64, 0, stream>>>(o_ne, goff, gemb, nullptr);
  k_assign<<<Gg, 64, 0, stream>>>(gemb, proto, pnorm, assign);
  k_mm<256, true, 1><<<gmm, 256, 0, stream>>>(neh, nel, Wm1th, Wm1tl, nullptr, nullptr,
                                              nullptr, nullptr, pcb, batch, assign,
                                              Wm2, prob);
  k_bern<<<nB, 256, 0, stream>>>(prob, bm2, o_nb, accs);
  k_eb<<<eB, 256, 0, stream>>>(src, dst, o_nb, o_eb, accs);

  // ---- pass 2 (plain bf16 GEMMs, bf16 chunked gathers) ----
  // x->bf16 AFTER the masker GEMM: xbf aliases nel (see above).
  k_cvtbf4<<<(Nn * 128 / 4 + 255) / 256, 256, 0, stream>>>((const float4*)x,
                                                           (ushort4*)xbf, Nn * 128 / 4);
  k_aggc<128, 1, true, false><<<1250 * 2, 256, 0, stream>>>(xbf, o_nb, offs, csr, a1bh, nullptr);
  k_mm<128, false, 0><<<gmm, 256, 0, stream>>>(a1bh, nullptr, W1th, nullptr, b1, nullptr,
                                               h1b, nullptr, nullptr, nullptr, nullptr,
                                               nullptr, nullptr);
  k_aggc<256, 2, true, false><<<1250 * 4, 256, 0, stream>>>(h1b, o_nb, offs, csr, a2bh, nullptr);
  k_mm<256, false, 0><<<gmm, 256, 0, stream>>>(a2bh, nullptr, W2th, nullptr, b2, bufB,
                                               nullptr, nullptr, nullptr, nullptr,
                                               nullptr, nullptr, nullptr);
  k_pool<<<dim3(Gg, 4), 64, 0, stream>>>(bufB, goff, sgemb, o_sg);

  k_simnce<<<Gg, 64, 0, stream>>>(sgemb, proto, pnorm, o_sim, snorm, accs + 2);
  k_fin<<<1, 1, 0, stream>>>(accs, o_kl, o_nce);
  k_datasim<<<Gg, 256, 0, stream>>>(sgemb, snorm, o_ds);
}